// Round 9
// baseline (160.978 us; speedup 1.0000x reference)
//
#include <hip/hip_runtime.h>
#include <hip/hip_bf16.h>

typedef __bf16 bf16x8 __attribute__((ext_vector_type(8)));
typedef float  f32x4  __attribute__((ext_vector_type(4)));
typedef float  f32x16 __attribute__((ext_vector_type(16)));

constexpr int Bn = 8192, Dn = 64, On = 256;

// async global->LDS DMA (not demotable by regalloc; dest = uniform base + lane*size)
#define GLD16(g, l) __builtin_amdgcn_global_load_lds( \
    (const __attribute__((address_space(1))) void*)(g), \
    (__attribute__((address_space(3))) void*)(l), 16, 0, 0)
#define GLD4(g, l) __builtin_amdgcn_global_load_lds( \
    (const __attribute__((address_space(1))) void*)(g), \
    (__attribute__((address_space(3))) void*)(l), 4, 0, 0)

// ---- prep: bTsw[o][e][slot] = betaT chunk-XOR-swizzled bf16 A-image;
//      ncpk[o][64] = -c_proj packed in 32x32 C-register order ----
__global__ void k_prep(const float* __restrict__ betas, const float* __restrict__ centers,
                       __bf16* __restrict__ bTsw, float* __restrict__ ncpk) {
    __shared__ float s[64 * 65];                        // +1 pad transpose buffer
    const int o = blockIdx.x, tid = threadIdx.x;
    const float* bo = betas + (size_t)o * 4096;         // betas[o][d][e]
    for (int j = tid; j < 1024; j += 256) {
        int d = j >> 4, e4 = (j & 15) * 4;
        float4 v = ((const float4*)bo)[j];
        s[d * 65 + e4 + 0] = v.x; s[d * 65 + e4 + 1] = v.y;
        s[d * 65 + e4 + 2] = v.z; s[d * 65 + e4 + 3] = v.w;
    }
    __syncthreads();
    // row e (128B), chunk c (16B, d=8c..8c+7) stored at slot c^(e&7)
    for (int j = tid; j < 4096; j += 256) {
        int e = j >> 6, dpos = j & 63;
        int slot = dpos >> 3, jj = dpos & 7;
        int d = ((slot ^ (e & 7)) << 3) + jj;
        bTsw[(size_t)o * 4096 + j] = (__bf16)s[d * 65 + e];
    }
    // -cproj packed: [etile][l5][reg] -> e-row = 32*et + 4*l5 + (reg&3) + 8*(reg>>2)
    if (tid < 64) {
        int et = tid >> 5, rem = tid & 31, l5 = rem >> 4, reg = rem & 15;
        int row = et * 32 + l5 * 4 + (reg & 3) + ((reg >> 2) << 3);
        float acc = 0.f;
        for (int d = 0; d < 64; ++d) acc += s[d * 65 + row] * centers[o * 64 + d];
        ncpk[o * 64 + tid] = -acc;
    }
}

// ---- main (MEASUREMENT BUILD): R8 structure, o-loop replicated REP=5x so the
//      dispatch exceeds the ~44us top-5 cutoff and yields direct counters.
//      Stores are idempotent; every launch does identical work (graph-safe). ----
__global__ void __launch_bounds__(256)
__attribute__((amdgpu_waves_per_eu(2, 2)))
k_main(const float* __restrict__ x, const __bf16* __restrict__ bTsw,
       const float* __restrict__ ncpk, float* __restrict__ out) {
    __shared__ __align__(16) __bf16 sX[128 * 64];       // 16 KB, xor-swizzled
    __shared__ __align__(16) __bf16 sA[4][64 * 64];     // 8 KB per wave (private)
    __shared__ __align__(16) float  sCp[4][64];         // 256 B per wave

    const int tid = threadIdx.x, wq = tid >> 6, lane = tid & 63;
    const int l31 = lane & 31, l5 = lane >> 5;
    const int bbase = blockIdx.x * 128;
    const int o0 = blockIdx.y * 32 + wq * 8;

    // stage x fp32 -> bf16, chunk (rb, c) at slot c^(rb&7)
#pragma unroll
    for (int i = 0; i < 4; ++i) {
        int id = i * 256 + tid, rb = id >> 3, c = id & 7;
        const float* xp = x + (size_t)(bbase + rb) * 64 + c * 8;
        float4 v0 = *(const float4*)xp, v1 = *(const float4*)(xp + 4);
        bf16x8 f;
        f[0] = (__bf16)v0.x; f[1] = (__bf16)v0.y; f[2] = (__bf16)v0.z; f[3] = (__bf16)v0.w;
        f[4] = (__bf16)v1.x; f[5] = (__bf16)v1.y; f[6] = (__bf16)v1.z; f[7] = (__bf16)v1.w;
        *(bf16x8*)(sX + rb * 64 + ((c ^ (rb & 7)) << 3)) = f;
    }
    __syncthreads();                                    // the only block barrier

    // resident x-fragments: B-operand, lane: n = l31, k = l5*8+j (K=16/step)
    bf16x8 xf[4][4];                                    // [btile][kstep] = 64 VGPR
#pragma unroll
    for (int bt = 0; bt < 4; ++bt)
#pragma unroll
        for (int k = 0; k < 4; ++k) {
            int row = bt * 32 + l31, c = k * 2 + l5;
            xf[bt][k] = *(const bf16x8*)(sX + row * 64 + ((c ^ (row & 7)) << 3));
        }

    __bf16* myA  = &sA[wq][0];
    float*  myCp = &sCp[wq][0];

#pragma unroll 1
    for (int rep = 0; rep < 5; ++rep) {                 // MEASUREMENT replication
#pragma unroll 1
    for (int oi = 0; oi < 8; ++oi) {
        const int o = o0 + oi;
        const __bf16* gA = bTsw + (size_t)o * 4096 + lane * 8;
#pragma unroll
        for (int cll = 0; cll < 8; ++cll)               // 8 KB A-image, 9-deep async batch
            GLD16(gA + cll * 512, myA + cll * 512);
        GLD4(ncpk + o * 64 + lane, myCp);
        __builtin_amdgcn_sched_barrier(0);
        __builtin_amdgcn_s_waitcnt(0x0f70);             // vmcnt(0): DMA landed
        __builtin_amdgcn_sched_barrier(0);

        f32x4 qv[4] = {{0.f,0.f,0.f,0.f},{0.f,0.f,0.f,0.f},{0.f,0.f,0.f,0.f},{0.f,0.f,0.f,0.f}};
#pragma unroll
        for (int et = 0; et < 2; ++et) {
            f32x16 cpv;                                 // C-init = -cp in C-reg order
#pragma unroll
            for (int r4 = 0; r4 < 4; ++r4)
                ((f32x4*)&cpv)[r4] = *(const f32x4*)(myCp + et * 32 + l5 * 16 + r4 * 4);
            bf16x8 af[4];                               // A-operand: m = l31, k = l5*8+j
#pragma unroll
            for (int k = 0; k < 4; ++k) {
                int row = et * 32 + l31, c = k * 2 + l5;
                af[k] = *(const bf16x8*)(myA + row * 64 + ((c ^ (row & 7)) << 3));
            }
#pragma unroll
            for (int bt = 0; bt < 4; ++bt) {
                f32x16 acc = __builtin_amdgcn_mfma_f32_32x32x16_bf16(af[0], xf[bt][0], cpv, 0, 0, 0);
                acc = __builtin_amdgcn_mfma_f32_32x32x16_bf16(af[1], xf[bt][1], acc, 0, 0, 0);
                acc = __builtin_amdgcn_mfma_f32_32x32x16_bf16(af[2], xf[bt][2], acc, 0, 0, 0);
                acc = __builtin_amdgcn_mfma_f32_32x32x16_bf16(af[3], xf[bt][3], acc, 0, 0, 0);
#pragma unroll
                for (int j = 0; j < 16; ++j)            // qv += (y-cp)^2
                    qv[bt][j & 3] = fmaf(acc[j], acc[j], qv[bt][j & 3]);
            }
        }
        float q[4];
#pragma unroll
        for (int bt = 0; bt < 4; ++bt) {                // one shuffle per btile
            float qs = (qv[bt][0] + qv[bt][1]) + (qv[bt][2] + qv[bt][3]);
            qs += __shfl_xor(qs, 32, 64);
            q[bt] = qs;
        }
        float qA = l5 ? q[2] : q[0], qB = l5 ? q[3] : q[1];
        int bA = bbase + l5 * 64 + l31;                 // lane stores btiles {2*l5, 2*l5+1}
        out[(size_t)bA * 256 + o]        = __expf(-qA);
        out[(size_t)(bA + 32) * 256 + o] = __expf(-qB);
        __builtin_amdgcn_sched_barrier(0);              // pin: next DMA can't pass my reads
    }
    }
}

extern "C" void kernel_launch(void* const* d_in, const int* in_sizes, int n_in,
                              void* d_out, int out_size, void* d_ws, size_t ws_size,
                              hipStream_t stream) {
    const float* x       = (const float*)d_in[0];   // [8192,64]
    const float* centers = (const float*)d_in[1];   // [256,1,64]
    const float* betas   = (const float*)d_in[2];   // [256,64,64]
    float* out = (float*)d_out;                     // [8192,256] fp32

    char* ws = (char*)d_ws;
    __bf16* bTsw = (__bf16*)ws;                     // 2 MB (swizzled A-images)
    float*  ncpk = (float*)(ws + 2 * (1 << 20));    // 64 KB (packed -cproj)

    k_prep<<<dim3(On),           dim3(256), 0, stream>>>(betas, centers, bTsw, ncpk);
    k_main<<<dim3(Bn / 128, On / 32), dim3(256), 0, stream>>>(x, bTsw, ncpk, out);
}

// Round 10
// 87.518 us; speedup vs baseline: 1.8394x; 1.8394x over previous
//
#include <hip/hip_runtime.h>
#include <hip/hip_bf16.h>

typedef __bf16 bf16x8 __attribute__((ext_vector_type(8)));
typedef float  f32x4  __attribute__((ext_vector_type(4)));
typedef float  f32x16 __attribute__((ext_vector_type(16)));

constexpr int Bn = 8192, Dn = 64, On = 256;

// async global->LDS DMA: lds dst = wave-uniform base, HW adds lane*16
#define GLD16(g, l) __builtin_amdgcn_global_load_lds( \
    (const __attribute__((address_space(1))) void*)(g), \
    (__attribute__((address_space(3))) void*)(l), 16, 0, 0)

// ---- prep: bTsw[o] = A-image in EXACT read order: chunk((et*4+k)*64+lane) =
//      betaT[e = et*32+(lane&31)][d = (k*2+(lane>>5))*8 .. +7]  -> both the
//      GLD16 writes and the af ds_read_b128 are stride-1 (conflict-free).
//      ncpk[o][64] = -c_proj packed in 32x32 C-register order. ----
__global__ void k_prep(const float* __restrict__ betas, const float* __restrict__ centers,
                       __bf16* __restrict__ bTsw, float* __restrict__ ncpk) {
    __shared__ float s[64 * 65];                        // +1 pad transpose buffer
    const int o = blockIdx.x, tid = threadIdx.x;
    const float* bo = betas + (size_t)o * 4096;         // betas[o][d][e]
    for (int j = tid; j < 1024; j += 256) {
        int d = j >> 4, e4 = (j & 15) * 4;
        float4 v = ((const float4*)bo)[j];
        s[d * 65 + e4 + 0] = v.x; s[d * 65 + e4 + 1] = v.y;
        s[d * 65 + e4 + 2] = v.z; s[d * 65 + e4 + 3] = v.w;
    }
    __syncthreads();
    for (int p = tid; p < 4096; p += 256) {
        int chunk = p >> 3, j = p & 7;
        int ek = chunk >> 6, lane = chunk & 63;         // ek = et*4 + k
        int e = (ek >> 2) * 32 + (lane & 31);
        int d = ((ek & 3) * 2 + (lane >> 5)) * 8 + j;
        bTsw[(size_t)o * 4096 + p] = (__bf16)s[d * 65 + e];
    }
    // -cproj packed: [et][l5][reg] -> e-row = 32*et + 4*l5 + (reg&3) + 8*(reg>>2)
    if (tid < 64) {
        int et = tid >> 5, rem = tid & 31, l5 = rem >> 4, reg = rem & 15;
        int row = et * 32 + l5 * 4 + (reg & 3) + ((reg >> 2) << 3);
        float acc = 0.f;
        for (int d = 0; d < 64; ++d) acc += s[d * 65 + row] * centers[o * 64 + d];
        ncpk[o * 64 + tid] = -acc;
    }
}

// ---- main: block = 4 waves x 512 b, 8 o sequential. A block-shared, DMA
//      double-buffered, barrier-paced (prefetch o+1 lands during compute o).
//      Packed-f32 squaring; zero in-loop global stores; LDS-transpose epilogue. ----
__global__ void __launch_bounds__(256)
__attribute__((amdgpu_waves_per_eu(2, 2)))
k_main(const float* __restrict__ x, const __bf16* __restrict__ bTsw,
       const float* __restrict__ ncpk, float* __restrict__ out) {
    __shared__ __align__(16) unsigned char smem[2 * 8192 + 2048];   // 18.4 KB
    __bf16* sA0 = (__bf16*)smem;
    __bf16* sA1 = (__bf16*)(smem + 8192);
    float*  sCp = (float*)(smem + 16384);               // 8 o x 64 packed -cp

    const int tid = threadIdx.x, wq = tid >> 6, lane = tid & 63;
    const int l31 = lane & 31, l5 = lane >> 5;
    const int bbase = blockIdx.x * 512;                 // grid: x = b-strip (16)
    const int o0 = blockIdx.y * 8;                      // y = o-group (32); id+-16 = same XCD

    sCp[tid]       = ncpk[o0 * 64 + tid];
    sCp[256 + tid] = ncpk[o0 * 64 + 256 + tid];

    // x-fragments straight from global (one-time), B-operand layout
    bf16x8 xf[4][4];                                    // [bt][kstep] = 64 VGPR
#pragma unroll
    for (int bt = 0; bt < 4; ++bt)
#pragma unroll
        for (int kk = 0; kk < 4; ++kk) {
            const float* xp = x + (size_t)(bbase + wq * 128 + bt * 32 + l31) * 64
                                + (kk * 2 + l5) * 8;
            float4 v0 = *(const float4*)xp, v1 = *(const float4*)(xp + 4);
            bf16x8 f;
            f[0] = (__bf16)v0.x; f[1] = (__bf16)v0.y; f[2] = (__bf16)v0.z; f[3] = (__bf16)v0.w;
            f[4] = (__bf16)v1.x; f[5] = (__bf16)v1.y; f[6] = (__bf16)v1.z; f[7] = (__bf16)v1.w;
            xf[bt][kk] = f;
        }

    // each wave DMAs its quarter (2 KB) of the 8 KB A-image
    auto prefetch = [&](int o, __bf16* buf) {
        const __bf16* g = bTsw + (size_t)o * 4096;
        GLD16(g + (size_t)(wq * 128 + lane) * 8,      buf + (wq * 128) * 8);
        GLD16(g + (size_t)(wq * 128 + 64 + lane) * 8, buf + (wq * 128 + 64) * 8);
    };

    float qd[16];                                       // deferred q: [oi][2 rows]
    prefetch(o0, sA0);
    __builtin_amdgcn_s_waitcnt(0x0f70);                 // vmcnt(0)
    __syncthreads();

#pragma unroll
    for (int oi = 0; oi < 8; ++oi) {
        __bf16* cur = (oi & 1) ? sA1 : sA0;
        if (oi < 7) prefetch(o0 + oi + 1, (oi & 1) ? sA0 : sA1);

        f32x4 qv[4] = {{0,0,0,0},{0,0,0,0},{0,0,0,0},{0,0,0,0}};
#pragma unroll
        for (int et = 0; et < 2; ++et) {
            f32x16 cpv;                                 // C-init = -cp (C-reg order)
#pragma unroll
            for (int r4 = 0; r4 < 4; ++r4)
                ((f32x4*)&cpv)[r4] = *(const f32x4*)(sCp + oi * 64 + et * 32 + l5 * 16 + r4 * 4);
            bf16x8 af[4];                               // stride-1 ds_read_b128
#pragma unroll
            for (int k = 0; k < 4; ++k)
                af[k] = *(const bf16x8*)(cur + (size_t)((et * 4 + k) * 64 + lane) * 8);
#pragma unroll
            for (int bt = 0; bt < 4; ++bt) {
                f32x16 acc = __builtin_amdgcn_mfma_f32_32x32x16_bf16(af[0], xf[bt][0], cpv, 0, 0, 0);
                acc = __builtin_amdgcn_mfma_f32_32x32x16_bf16(af[1], xf[bt][1], acc, 0, 0, 0);
                acc = __builtin_amdgcn_mfma_f32_32x32x16_bf16(af[2], xf[bt][2], acc, 0, 0, 0);
                acc = __builtin_amdgcn_mfma_f32_32x32x16_bf16(af[3], xf[bt][3], acc, 0, 0, 0);
                const f32x4* aq = (const f32x4*)&acc;   // packed v_pk_fma_f32 squaring
                qv[bt] += aq[0] * aq[0];
                qv[bt] += aq[1] * aq[1];
                qv[bt] += aq[2] * aq[2];
                qv[bt] += aq[3] * aq[3];
            }
        }
        float q[4];
#pragma unroll
        for (int bt = 0; bt < 4; ++bt) {
            float qs = (qv[bt][0] + qv[bt][1]) + (qv[bt][2] + qv[bt][3]);
            qs += __shfl_xor(qs, 32, 64);               // merge l5 halves (full 64-e sum)
            q[bt] = qs;
        }
        qd[oi * 2 + 0] = l5 ? q[2] : q[0];              // lane's rows: bt = 2*l5, 2*l5+1
        qd[oi * 2 + 1] = l5 ? q[3] : q[1];

        __builtin_amdgcn_sched_barrier(0);
        __builtin_amdgcn_s_waitcnt(0x0f70);             // my prefetch landed (issued ~800 cyc ago)
        __syncthreads();                                // all waves' quarters landed; cur free
    }

    // epilogue: per-wave LDS transpose (rows padded to 9 floats), coalesced stores
    float* scr = (float*)smem + wq * 1152;              // 128 rows x 9 floats per wave
#pragma unroll
    for (int oi = 0; oi < 8; ++oi) {
        scr[(l5 * 64 + l31) * 9 + oi]      = qd[oi * 2 + 0];
        scr[(l5 * 64 + 32 + l31) * 9 + oi] = qd[oi * 2 + 1];
    }
    __syncthreads();
#pragma unroll
    for (int rr = 0; rr < 2; ++rr) {
        int r = lane * 2 + rr;                          // row within wave's 128
        const float* q8 = scr + r * 9;
        f32x4 r0, r1;
#pragma unroll
        for (int j = 0; j < 4; ++j) { r0[j] = __expf(-q8[j]); r1[j] = __expf(-q8[4 + j]); }
        float* op = out + (size_t)(bbase + wq * 128 + r) * 256 + o0;
        *(f32x4*)op       = r0;                         // 32 B burst per row
        *(f32x4*)(op + 4) = r1;
    }
}

extern "C" void kernel_launch(void* const* d_in, const int* in_sizes, int n_in,
                              void* d_out, int out_size, void* d_ws, size_t ws_size,
                              hipStream_t stream) {
    const float* x       = (const float*)d_in[0];   // [8192,64]
    const float* centers = (const float*)d_in[1];   // [256,1,64]
    const float* betas   = (const float*)d_in[2];   // [256,64,64]
    float* out = (float*)d_out;                     // [8192,256] fp32

    char* ws = (char*)d_ws;
    __bf16* bTsw = (__bf16*)ws;                     // 2 MB (read-order A-images)
    float*  ncpk = (float*)(ws + 2 * (1 << 20));    // 64 KB (packed -cproj)

    k_prep<<<dim3(On),                dim3(256), 0, stream>>>(betas, centers, bTsw, ncpk);
    k_main<<<dim3(Bn / 512, On / 8),  dim3(256), 0, stream>>>(x, bTsw, ncpk, out);
}